// Round 3
// baseline (504.398 us; speedup 1.0000x reference)
//
#include <hip/hip_runtime.h>
#include <hip/hip_bf16.h>
#include <stdint.h>

#define N_TOKENS   65536
#define IN_FEAT    512
#define OUT_FEAT   512
#define NUM_EXPERT 64
#define BM 128
#define BN 128
#define BK 32
#define SK 36                    // padded LDS stride (mid-path kernel only)
#define K_STEPS (IN_FEAT / BK)   // 16
#define MAX_TILES 640            // true worst case: 512 + 64 = 576 tiles
#define NCOL (OUT_FEAT / BN)     // 4

// ws layout (int32 units), meta footprint identical to prior rounds:
//   [197] tile_count  [200..1928) tiles (e,start,cnt)x576  [2048..) order ushort[65536]
// BIG extension (byte offsets):
//   [147456 ..)              Asorted: bf16 rows in expert-sorted order (67,108,864 B)
//   [147456+2*INP_ELEMS ..)  bf16 copy of weight (33,554,432 B)
#define WS_NTILES 197
#define WS_TILES  200
#define WS_ORDER  2048
#define WS_NEEDED (2048 * 4 + 131072)

#define INP_ELEMS (N_TOKENS * IN_FEAT)               // 33,554,432
#define W_ELEMS   (NUM_EXPERT * OUT_FEAT * IN_FEAT)  // 16,777,216
#define WS_BF16_OFF 147456
#define WS_BIG ((size_t)WS_BF16_OFF + 2ull * INP_ELEMS + 2ull * W_ELEMS)  // ~100.8 MB

#define PREP_T 512
#define TOK_PER_ITER (PREP_T * 4)            // 2048
#define NITER (N_TOKENS / TOK_PER_ITER)      // 32
#define WCONV_BLKS 512

typedef __attribute__((ext_vector_type(8))) short bf16x8;
typedef __attribute__((ext_vector_type(4))) float f32x4;

__device__ __forceinline__ float b2f(short v) {
    union { float f; unsigned u; } z;
    z.u = ((unsigned)(unsigned short)v) << 16;
    return z.f;
}

__device__ __forceinline__ unsigned pk2(float a, float b) {
    union { __hip_bfloat16 h; unsigned short u; } x, y;
    x.h = __float2bfloat16(a);
    y.h = __float2bfloat16(b);
    return ((unsigned)y.u << 16) | (unsigned)x.u;
}

__device__ __forceinline__ unsigned short f2bu(float a) {
    union { __hip_bfloat16 h; unsigned short u; } x;
    x.h = __float2bfloat16(a);
    return x.u;
}

// async global->LDS, 16B per lane; LDS dest is wave-uniform base + lane*16
__device__ __forceinline__ void gll16(const void* g, short* l) {
    __builtin_amdgcn_global_load_lds(
        (const __attribute__((address_space(1))) unsigned*)g,
        (__attribute__((address_space(3))) unsigned*)l, 16, 0, 0);
}

// dtype detect, executed by one wave (lanes 0..63): bf16-pair data has low-u16
// exponent fields in the plausible band; fp32 low-u16 is random mantissa bits.
// Deterministic (fixed shuffle-reduce order), identical in every block.
__device__ __forceinline__ int detect_wave(const unsigned* __restrict__ inw, int lane) {
    int cnt = 0;
    #pragma unroll
    for (int i = 0; i < 16; ++i) {
        unsigned u = inw[lane * 16 + i];
        unsigned lo = u & 0xFFFFu;
        unsigned ec = (lo >> 7) & 0xFFu;
        if (lo == 0u || (ec >= 90u && ec <= 131u)) cnt++;
    }
    #pragma unroll
    for (int d = 32; d > 0; d >>= 1) cnt += __shfl_down(cnt, d, 64);
    return (cnt >= 512) ? 0 : 1;   // valid on lane 0: 0=bf16, 1=fp32
}

// ---------------------------------------------------------------------------
// k_prep: the ENTIRE aux chain in one kernel.
//   blocks 0..63   : expert e = blockIdx.x. Ballot/prefix compaction of gate
//                    (no atomics except block-private LDS hist), writes order,
//                    its own tile descriptors, and (big) copies+converts its
//                    tokens' inp rows into Asorted (sequential bf16 rows).
//   blocks 64..575 : (big only) fp32->bf16 weight conversion.
// ---------------------------------------------------------------------------
__global__ __launch_bounds__(PREP_T) void k_prep(
        const int* __restrict__ gate,
        const void* __restrict__ inp_,
        const void* __restrict__ weight_,
        int* __restrict__ ws,
        int big) {
    __shared__ int hist[NUM_EXPERT];
    __shared__ int wcnt[NITER * 8];   // per-(iter,wave) count of OUR expert -> exclusive bases
    __shared__ int sOff, sCnt, sFlag;
    int t = threadIdx.x;
    int lane = t & 63;
    int w = t >> 6;

    if (t < 64) {
        int f = detect_wave((const unsigned*)inp_, lane);
        if (t == 0) sFlag = f;
    }
    if (t < NUM_EXPERT) hist[t] = 0;
    __syncthreads();
    int flag = sFlag;

    if (blockIdx.x >= 64) {
        // ---- weight conversion role ----
        if (!big || flag != 1) return;
        const float* wf = (const float*)weight_;
        short* bw = (short*)((char*)ws + WS_BF16_OFF) + INP_ELEMS;
        const int NCHUNK = W_ELEMS / 8;            // 8 floats -> 8 bf16 per chunk
        int idx = (blockIdx.x - 64) * PREP_T + t;
        for (int c = idx; c < NCHUNK; c += WCONV_BLKS * PREP_T) {
            int f8 = c * 8;
            const float4* s = (const float4*)(wf + f8);
            float4 x = s[0], y = s[1];
            *(uint4*)(bw + f8) = (uint4){pk2(x.x, x.y), pk2(x.z, x.w),
                                         pk2(y.x, y.y), pk2(y.z, y.w)};
        }
        return;
    }

    // ---- compaction role: one block per expert ----
    int e = blockIdx.x;
    unsigned short* order = (unsigned short*)(ws + WS_ORDER);

    // pass 1: block-private hist of ALL experts + per-(iter,wave) counts of e
    for (int it = 0; it < NITER; ++it) {
        int4 g = *((const int4*)(gate + it * TOK_PER_ITER) + t);
        int g0 = g.x & 63, g1 = g.y & 63, g2 = g.z & 63, g3 = g.w & 63;
        atomicAdd(&hist[g0], 1); atomicAdd(&hist[g1], 1);
        atomicAdd(&hist[g2], 1); atomicAdd(&hist[g3], 1);
        int c = (g0 == e) + (g1 == e) + (g2 == e) + (g3 == e);
        #pragma unroll
        for (int d = 32; d > 0; d >>= 1) c += __shfl_down(c, d, 64);
        if (lane == 0) wcnt[it * 8 + w] = c;
    }
    __syncthreads();

    if (t < 64) {
        // offsets + tile bases from hist (redundant per block, all derive same)
        int h = hist[lane];
        int ph = h;
        #pragma unroll
        for (int d = 1; d < 64; d <<= 1) { int v = __shfl_up(ph, d, 64); if (lane >= d) ph += v; }
        int off_l = ph - h;                       // exclusive token prefix
        int nt_l = (h + BM - 1) >> 7;
        int pt = nt_l;
        #pragma unroll
        for (int d = 1; d < 64; d <<= 1) { int v = __shfl_up(pt, d, 64); if (lane >= d) pt += v; }
        int tb_l = pt - nt_l;                     // exclusive tile prefix
        int off_e = __shfl(off_l, e, 64);
        int cnt_e = __shfl(h, e, 64);
        int tb_e  = __shfl(tb_l, e, 64);
        int nt_e  = __shfl(nt_l, e, 64);
        int tot_t = __shfl(pt, 63, 64);
        if (lane == 0) { sOff = off_e; sCnt = cnt_e; }
        for (int j = lane; j < nt_e; j += 64) {
            int* tp = ws + WS_TILES + (tb_e + j) * 3;
            tp[0] = e;
            tp[1] = off_e + j * BM;
            int rem = cnt_e - j * BM;
            tp[2] = rem < BM ? rem : BM;
        }
        if (e == 0 && lane == 0) ws[WS_NTILES] = tot_t;

        // exclusive scan of wcnt[256] (iter-major order)
        int v0 = wcnt[lane * 4], v1 = wcnt[lane * 4 + 1],
            v2 = wcnt[lane * 4 + 2], v3 = wcnt[lane * 4 + 3];
        int s1 = v0, s2 = s1 + v1, s3 = s2 + v2, tot = s3 + v3;
        int inc = tot;
        #pragma unroll
        for (int d = 1; d < 64; d <<= 1) { int v = __shfl_up(inc, d, 64); if (lane >= d) inc += v; }
        int b0 = inc - tot;
        wcnt[lane * 4] = b0; wcnt[lane * 4 + 1] = b0 + s1;
        wcnt[lane * 4 + 2] = b0 + s2; wcnt[lane * 4 + 3] = b0 + s3;
    }
    __syncthreads();
    int off = sOff, cnt = sCnt;

    // pass 2: write order (block-sequential region [off, off+cnt), no atomics)
    for (int it = 0; it < NITER; ++it) {
        int4 g = *((const int4*)(gate + it * TOK_PER_ITER) + t);
        int m0 = (g.x & 63) == e, m1 = (g.y & 63) == e,
            m2 = (g.z & 63) == e, m3 = (g.w & 63) == e;
        int c = m0 + m1 + m2 + m3;
        int p = c;
        #pragma unroll
        for (int d = 1; d < 64; d <<= 1) { int v = __shfl_up(p, d, 64); if (lane >= d) p += v; }
        int base = off + wcnt[it * 8 + w] + (p - c);
        int tokb = it * TOK_PER_ITER + t * 4;
        if (m0) { if ((unsigned)base < N_TOKENS) order[base] = (unsigned short)tokb;       base++; }
        if (m1) { if ((unsigned)base < N_TOKENS) order[base] = (unsigned short)(tokb + 1); base++; }
        if (m2) { if ((unsigned)base < N_TOKENS) order[base] = (unsigned short)(tokb + 2); base++; }
        if (m3) { if ((unsigned)base < N_TOKENS) order[base] = (unsigned short)(tokb + 3); base++; }
    }

    // copy phase (big only): gather+convert this expert's rows into Asorted.
    // One wave per row: fp32 row = 2KB read -> 1KB bf16 write.
    if (!big || cnt == 0) return;
    __syncthreads();   // order writes (this block's) drained before readback
    short* Asrt = (short*)((char*)ws + WS_BF16_OFF);
    if (flag) {
        for (int i = w; i < cnt; i += 8) {
            int tok = order[off + i];
            const float4* src = (const float4*)((const float*)inp_ + (size_t)tok * IN_FEAT) + lane * 2;
            float4 x = src[0], y = src[1];
            *((uint4*)(Asrt + (size_t)(off + i) * IN_FEAT) + lane) =
                (uint4){pk2(x.x, x.y), pk2(x.z, x.w), pk2(y.x, y.y), pk2(y.z, y.w)};
        }
    } else {
        for (int i = w; i < cnt; i += 8) {
            int tok = order[off + i];
            const uint4* src = (const uint4*)((const short*)inp_ + (size_t)tok * IN_FEAT) + lane;
            *((uint4*)(Asrt + (size_t)(off + i) * IN_FEAT) + lane) = *src;
        }
    }
}

// ---------- BIG path GEMM: pure-bf16, global_load_lds staging, SEQUENTIAL A ----------
// A rows come from Asorted (expert-sorted), so staging addresses are start+row —
// no gather indirection on the load path. Source-side XOR swizzle + same XOR on
// frag reads (rule #21) keeps ds_read_b128 at 2 lanes/bank (free).
__global__ __launch_bounds__(256) void k_moe_gemm_big(
        const void* __restrict__ inp_,
        const void* __restrict__ weight_,
        void* __restrict__ out_,
        const int* __restrict__ ws) {
    __shared__ __align__(16) short sA[BM * BK];  // 8 KB linear
    __shared__ __align__(16) short sB[BN * BK];  // 8 KB linear
    __shared__ int sTok[BM];
    __shared__ int sFlag;

    int tid = threadIdx.x;
    int lane = tid & 63;
    if (tid < 64) {
        int f = detect_wave((const unsigned*)inp_, lane);
        if (tid == 0) sFlag = f;
    }
    __syncthreads();
    int flag = sFlag;

    int ntiles = ws[WS_NTILES];
    if (ntiles > MAX_TILES) ntiles = MAX_TILES;
    int items = ntiles * NCOL;
    const unsigned short* order = (const unsigned short*)(ws + WS_ORDER);
    const short* Asrt = (const short*)((const char*)ws + WS_BF16_OFF);
    const short* Wb = flag ? Asrt + INP_ELEMS : (const short*)weight_;

    int w = tid >> 6;
    int wm = (w >> 1) * 64;
    int wn = (w & 1) * 64;
    int l15 = lane & 15;
    int quad = lane >> 4;

    // frag read addresses: row-major linear + XOR'd 16B chunk
    int rowA = wm + l15;
    const short* sAr = &sA[rowA * BK + (quad ^ ((rowA >> 1) & 3)) * 8];
    int rowB = wn + l15;
    const short* sBr = &sB[rowB * BK + (quad ^ ((rowB >> 1) & 3)) * 8];

    // staging roles: wave w stages 1KB segments {2w, 2w+1} of A and B
    int sr = lane >> 2;
    int cl = lane & 3;
    int rS0 = w * 32 + sr;
    int rS1 = rS0 + 16;
    int cg0 = cl ^ ((rS0 >> 1) & 3);
    int cg1 = cl ^ ((rS1 >> 1) & 3);
    short* dA0 = &sA[(w * 2 + 0) * 512];
    short* dA1 = &sA[(w * 2 + 1) * 512];
    short* dB0 = &sB[(w * 2 + 0) * 512];
    short* dB1 = &sB[(w * 2 + 1) * 512];

    for (int item = blockIdx.x; item < items; item += gridDim.x) {
        int tIdx = item >> 2;
        int n0 = (item & 3) * BN;
        const int* tile = ws + WS_TILES + tIdx * 3;
        int e = tile[0] & 63;
        int start = tile[1];
        int cnt = tile[2];
        cnt = cnt < 1 ? 1 : (cnt > BM ? BM : cnt);
        if (start < 0) start = 0;
        if (start > N_TOKENS - cnt) start = N_TOKENS - cnt;

        __syncthreads();   // protect sTok/sA/sB reuse across items
        if (tid < BM) {
            int r = tid < cnt ? tid : (cnt - 1);
            sTok[tid] = (int)order[start + r];   // epilogue scatter only
        }
        __syncthreads();

        int srow0 = start + rS0; if (srow0 > N_TOKENS - 1) srow0 = N_TOKENS - 1;
        int srow1 = start + rS1; if (srow1 > N_TOKENS - 1) srow1 = N_TOKENS - 1;
        const char* gA0 = (const char*)Asrt + (size_t)srow0 * (IN_FEAT * 2) + cg0 * 16;
        const char* gA1 = (const char*)Asrt + (size_t)srow1 * (IN_FEAT * 2) + cg1 * 16;
        size_t wbase = (size_t)e * OUT_FEAT * IN_FEAT;
        const char* gB0 = (const char*)(Wb + wbase + (size_t)(n0 + rS0) * IN_FEAT) + cg0 * 16;
        const char* gB1 = (const char*)(Wb + wbase + (size_t)(n0 + rS1) * IN_FEAT) + cg1 * 16;

        f32x4 acc[4][4];
        #pragma unroll
        for (int i = 0; i < 4; ++i)
            #pragma unroll
            for (int j = 0; j < 4; ++j)
                acc[i][j] = (f32x4){0.f, 0.f, 0.f, 0.f};

        for (int ks = 0; ks < K_STEPS; ++ks) {
            __syncthreads();
            gll16(gA0, dA0);
            gll16(gA1, dA1);
            gll16(gB0, dB0);
            gll16(gB1, dB1);
            gA0 += 64; gA1 += 64; gB0 += 64; gB1 += 64;
            __syncthreads();

            bf16x8 a[4], b[4];
            #pragma unroll
            for (int t = 0; t < 4; ++t) {
                a[t] = *(const bf16x8*)(sAr + t * 16 * BK);
                b[t] = *(const bf16x8*)(sBr + t * 16 * BK);
            }
            #pragma unroll
            for (int i = 0; i < 4; ++i)
                #pragma unroll
                for (int j = 0; j < 4; ++j)
                    acc[i][j] = __builtin_amdgcn_mfma_f32_16x16x32_bf16(a[i], b[j], acc[i][j], 0, 0, 0);
        }

        // epilogue: D col = lane&15, row = quad*4 + reg [m89/m91]; NT stores
        #pragma unroll
        for (int i = 0; i < 4; ++i) {
            int mb = wm + i * 16 + quad * 4;
            #pragma unroll
            for (int r = 0; r < 4; ++r) {
                int m = mb + r;
                if (m < cnt) {
                    int tok = sTok[m];
                    if (flag) {
                        float* orow = (float*)out_ + (size_t)tok * OUT_FEAT + n0 + wn + l15;
                        #pragma unroll
                        for (int j = 0; j < 4; ++j)
                            __builtin_nontemporal_store(acc[i][j][r], orow + j * 16);
                    } else {
                        unsigned short* orow = (unsigned short*)out_ + (size_t)tok * OUT_FEAT + n0 + wn + l15;
                        #pragma unroll
                        for (int j = 0; j < 4; ++j)
                            __builtin_nontemporal_store(f2bu(acc[i][j][r]), orow + j * 16);
                    }
                }
            }
        }
    }
}

// ---------- MID path (ws fits meta only): gathers from original inp/weight ----------
__global__ __launch_bounds__(256) void k_moe_gemm_mid(
        const void* __restrict__ inp_,
        const void* __restrict__ weight_,
        void* __restrict__ out_,
        const int* __restrict__ ws) {
    __shared__ __align__(16) short sA[BM * SK];
    __shared__ __align__(16) short sB[BN * SK];
    __shared__ int sTok[BM];
    __shared__ int sFlag;

    int tid = threadIdx.x;
    int lane = tid & 63;
    if (tid < 64) {
        int f = detect_wave((const unsigned*)inp_, lane);
        if (tid == 0) sFlag = f;
    }
    __syncthreads();
    int fp32 = sFlag;

    int ntiles = ws[WS_NTILES];
    if (ntiles > MAX_TILES) ntiles = MAX_TILES;
    int bx = blockIdx.y;
    if (bx >= ntiles) return;
    const int* tile = ws + WS_TILES + bx * 3;
    int e = tile[0] & 63;
    int start = tile[1];
    int cnt = tile[2];
    cnt = cnt < 1 ? 1 : (cnt > BM ? BM : cnt);
    if (start < 0) start = 0;
    if (start > N_TOKENS - cnt) start = N_TOKENS - cnt;
    int n0 = blockIdx.x * BN;
    const unsigned short* order = (const unsigned short*)(ws + WS_ORDER);

    if (tid < BM) {
        int r = tid < cnt ? tid : (cnt - 1);
        sTok[tid] = (int)order[start + r];
    }
    __syncthreads();

    int w = tid >> 6;
    int wm = (w >> 1) * 64;
    int wn = (w & 1) * 64;
    int l15 = lane & 15;
    int quad = lane >> 4;

    f32x4 acc[4][4];
    #pragma unroll
    for (int i = 0; i < 4; ++i)
        #pragma unroll
        for (int j = 0; j < 4; ++j)
            acc[i][j] = (f32x4){0.f, 0.f, 0.f, 0.f};

    const short* sAr = &sA[(wm + l15) * SK + quad * 8];
    const short* sBr = &sB[(wn + l15) * SK + quad * 8];

    if (fp32) {
        int ra = tid >> 1;
        int h = tid & 1;
        int tokA = sTok[ra];
        const float4* aG = (const float4*)((const float*)inp_ + (size_t)tokA * IN_FEAT) + h * 4;
        const float4* bG = (const float4*)((const float*)weight_ +
                           (size_t)(e * OUT_FEAT + n0 + ra) * IN_FEAT) + h * 4;
        uint4* sAd = (uint4*)&sA[ra * SK + h * 16];
        uint4* sBd = (uint4*)&sB[ra * SK + h * 16];

        for (int ks = 0; ks < K_STEPS; ++ks) {
            float4 a0 = aG[0], a1 = aG[1], a2 = aG[2], a3 = aG[3];
            float4 b0 = bG[0], b1 = bG[1], b2 = bG[2], b3 = bG[3];
            aG += 8; bG += 8;
            __syncthreads();
            sAd[0] = (uint4){pk2(a0.x, a0.y), pk2(a0.z, a0.w), pk2(a1.x, a1.y), pk2(a1.z, a1.w)};
            sAd[1] = (uint4){pk2(a2.x, a2.y), pk2(a2.z, a2.w), pk2(a3.x, a3.y), pk2(a3.z, a3.w)};
            sBd[0] = (uint4){pk2(b0.x, b0.y), pk2(b0.z, b0.w), pk2(b1.x, b1.y), pk2(b1.z, b1.w)};
            sBd[1] = (uint4){pk2(b2.x, b2.y), pk2(b2.z, b2.w), pk2(b3.x, b3.y), pk2(b3.z, b3.w)};
            __syncthreads();

            bf16x8 a[4], b[4];
            #pragma unroll
            for (int t = 0; t < 4; ++t) {
                a[t] = *(const bf16x8*)(sAr + t * 16 * SK);
                b[t] = *(const bf16x8*)(sBr + t * 16 * SK);
            }
            #pragma unroll
            for (int i = 0; i < 4; ++i)
                #pragma unroll
                for (int j = 0; j < 4; ++j)
                    acc[i][j] = __builtin_amdgcn_mfma_f32_16x16x32_bf16(a[i], b[j], acc[i][j], 0, 0, 0);
        }
    } else {
        int rr = tid >> 2;
        int qc = tid & 3;
        int tokA0 = sTok[rr];
        int tokA1 = sTok[rr + 64];
        const uint4* aG0 = (const uint4*)((const short*)inp_ + (size_t)tokA0 * IN_FEAT) + qc;
        const uint4* aG1 = (const uint4*)((const short*)inp_ + (size_t)tokA1 * IN_FEAT) + qc;
        const uint4* bG0 = (const uint4*)((const short*)weight_ +
                           (size_t)(e * OUT_FEAT + n0 + rr) * IN_FEAT) + qc;
        const uint4* bG1 = (const uint4*)((const short*)weight_ +
                           (size_t)(e * OUT_FEAT + n0 + rr + 64) * IN_FEAT) + qc;
        uint4* sAd0 = (uint4*)&sA[rr * SK + qc * 8];
        uint4* sAd1 = (uint4*)&sA[(rr + 64) * SK + qc * 8];
        uint4* sBd0 = (uint4*)&sB[rr * SK + qc * 8];
        uint4* sBd1 = (uint4*)&sB[(rr + 64) * SK + qc * 8];

        for (int ks = 0; ks < K_STEPS; ++ks) {
            uint4 va0 = *aG0, va1 = *aG1, vb0 = *bG0, vb1 = *bG1;
            aG0 += 4; aG1 += 4; bG0 += 4; bG1 += 4;
            __syncthreads();
            *sAd0 = va0; *sAd1 = va1; *sBd0 = vb0; *sBd1 = vb1;
            __syncthreads();

            bf16x8 a[4], b[4];
            #pragma unroll
            for (int t = 0; t < 4; ++t) {
                a[t] = *(const bf16x8*)(sAr + t * 16 * SK);
                b[t] = *(const bf16x8*)(sBr + t * 16 * SK);
            }
            #pragma unroll
            for (int i = 0; i < 4; ++i)
                #pragma unroll
                for (int j = 0; j < 4; ++j)
                    acc[i][j] = __builtin_amdgcn_mfma_f32_16x16x32_bf16(a[i], b[j], acc[i][j], 0, 0, 0);
        }
    }

    #pragma unroll
    for (int i = 0; i < 4; ++i) {
        int mb = wm + i * 16 + quad * 4;
        #pragma unroll
        for (int r = 0; r < 4; ++r) {
            int m = mb + r;
            if (m < cnt) {
                int tok = sTok[m];
                if (fp32) {
                    float* orow = (float*)out_ + (size_t)tok * OUT_FEAT + n0 + wn + l15;
                    #pragma unroll
                    for (int j = 0; j < 4; ++j)
                        __builtin_nontemporal_store(acc[i][j][r], orow + j * 16);
                } else {
                    unsigned short* orow = (unsigned short*)out_ + (size_t)tok * OUT_FEAT + n0 + wn + l15;
                    #pragma unroll
                    for (int j = 0; j < 4; ++j)
                        __builtin_nontemporal_store(f2bu(acc[i][j][r]), orow + j * 16);
                }
            }
        }
    }
}

// ws-light fallback: one block per token, VALU dot products
__global__ __launch_bounds__(256) void k_gemv(
        const void* __restrict__ inp_,
        const int* __restrict__ gate,
        const void* __restrict__ weight_,
        void* __restrict__ out_) {
    __shared__ float xf[IN_FEAT];
    __shared__ int sFlag;
    int t = threadIdx.x;
    if (t < 64) {
        int f = detect_wave((const unsigned*)inp_, t);
        if (t == 0) sFlag = f;
    }
    __syncthreads();
    int fp32 = sFlag;
    int tok = blockIdx.x;
    int e = gate[tok] & 63;
    if (fp32) {
        const float* xr = (const float*)inp_ + (size_t)tok * IN_FEAT;
        xf[2 * t] = xr[2 * t];
        xf[2 * t + 1] = xr[2 * t + 1];
        __syncthreads();
        #pragma unroll
        for (int rep = 0; rep < 2; ++rep) {
            int o = t + rep * 256;
            float s = 0.f;
            const float4* wr = (const float4*)((const float*)weight_ +
                               (size_t)(e * OUT_FEAT + o) * IN_FEAT);
            for (int k4 = 0; k4 < IN_FEAT / 4; ++k4) {
                float4 q = wr[k4];
                s += xf[4 * k4] * q.x + xf[4 * k4 + 1] * q.y
                   + xf[4 * k4 + 2] * q.z + xf[4 * k4 + 3] * q.w;
            }
            ((float*)out_)[(size_t)tok * OUT_FEAT + o] = s;
        }
    } else {
        const short* xr = (const short*)inp_ + (size_t)tok * IN_FEAT;
        xf[2 * t] = b2f(xr[2 * t]);
        xf[2 * t + 1] = b2f(xr[2 * t + 1]);
        __syncthreads();
        #pragma unroll
        for (int rep = 0; rep < 2; ++rep) {
            int o = t + rep * 256;
            float s = 0.f;
            const short4* wr = (const short4*)((const short*)weight_ +
                               (size_t)(e * OUT_FEAT + o) * IN_FEAT);
            for (int k4 = 0; k4 < IN_FEAT / 4; ++k4) {
                short4 q = wr[k4];
                s += xf[4 * k4] * b2f(q.x) + xf[4 * k4 + 1] * b2f(q.y)
                   + xf[4 * k4 + 2] * b2f(q.z) + xf[4 * k4 + 3] * b2f(q.w);
            }
            ((__hip_bfloat16*)out_)[(size_t)tok * OUT_FEAT + o] = __float2bfloat16(s);
        }
    }
}

extern "C" void kernel_launch(void* const* d_in, const int* in_sizes, int n_in,
                              void* d_out, int out_size, void* d_ws, size_t ws_size,
                              hipStream_t stream) {
    const void* inp    = d_in[0];
    const int*  gate   = (const int*)d_in[1];
    const void* weight = d_in[2];
    int* ws = (int*)d_ws;

    if (ws_size >= WS_BIG) {
        k_prep<<<64 + WCONV_BLKS, PREP_T, 0, stream>>>(gate, inp, weight, ws, 1);
        k_moe_gemm_big<<<2048, 256, 0, stream>>>(inp, weight, d_out, ws);
    } else if (ws_size >= (size_t)WS_NEEDED) {
        k_prep<<<64, PREP_T, 0, stream>>>(gate, inp, weight, ws, 0);
        dim3 grid(NCOL, MAX_TILES);
        k_moe_gemm_mid<<<grid, 256, 0, stream>>>(inp, weight, d_out, ws);
    } else {
        k_gemv<<<N_TOKENS, 256, 0, stream>>>(inp, gate, weight, d_out);
    }
}

// Round 4
// 359.624 us; speedup vs baseline: 1.4026x; 1.4026x over previous
//
#include <hip/hip_runtime.h>
#include <hip/hip_bf16.h>
#include <stdint.h>

#define N_TOKENS   65536
#define IN_FEAT    512
#define OUT_FEAT   512
#define NUM_EXPERT 64
#define BM 128
#define BN 128
#define BK 32
#define SK 36                    // padded LDS stride (mid-path kernel only)
#define K_STEPS (IN_FEAT / BK)   // 16
#define MAX_TILES 640            // true worst case: 512 + 64 = 576 tiles
#define NCOL (OUT_FEAT / BN)     // 4
#define NRANGE 256               // token ranges (256 tokens each)

// ws layout (int32 units):
//   [197] tile_count  [200..1928) tiles (e,start,cnt)x576
//   [2048..34816)  order ushort[65536] (128 KB)
//   [34816..51200) counts matrix cnt[range][expert] = 256x64 ints (64 KB)
// BIG extension (byte offsets):
//   [212992 ..)              Asorted: bf16 rows in expert-sorted order (67,108,864 B)
//   [212992+2*INP_ELEMS ..)  bf16 copy of weight (33,554,432 B)
#define WS_NTILES 197
#define WS_TILES  200
#define WS_ORDER  2048
#define WS_CNT    34816
#define WS_META_NEEDED 204800    // bytes: through end of counts matrix

#define INP_ELEMS (N_TOKENS * IN_FEAT)               // 33,554,432
#define W_ELEMS   (NUM_EXPERT * OUT_FEAT * IN_FEAT)  // 16,777,216
#define WS_BF16_OFF 212992
#define WS_BIG ((size_t)WS_BF16_OFF + 2ull * INP_ELEMS + 2ull * W_ELEMS)  // ~100.9 MB

typedef __attribute__((ext_vector_type(8))) short bf16x8;
typedef __attribute__((ext_vector_type(4))) float f32x4;

__device__ __forceinline__ float b2f(short v) {
    union { float f; unsigned u; } z;
    z.u = ((unsigned)(unsigned short)v) << 16;
    return z.f;
}

__device__ __forceinline__ unsigned pk2(float a, float b) {
    union { __hip_bfloat16 h; unsigned short u; } x, y;
    x.h = __float2bfloat16(a);
    y.h = __float2bfloat16(b);
    return ((unsigned)y.u << 16) | (unsigned)x.u;
}

__device__ __forceinline__ unsigned short f2bu(float a) {
    union { __hip_bfloat16 h; unsigned short u; } x;
    x.h = __float2bfloat16(a);
    return x.u;
}

// async global->LDS, 16B per lane; LDS dest is wave-uniform base + lane*16
__device__ __forceinline__ void gll16(const void* g, short* l) {
    __builtin_amdgcn_global_load_lds(
        (const __attribute__((address_space(1))) unsigned*)g,
        (__attribute__((address_space(3))) unsigned*)l, 16, 0, 0);
}

// dtype detect by one wave: bf16-pair data has low-u16 exponent fields in the
// plausible band; fp32 low-u16 is random mantissa bits. Deterministic.
__device__ __forceinline__ int detect_wave(const unsigned* __restrict__ inw, int lane) {
    int cnt = 0;
    #pragma unroll
    for (int i = 0; i < 16; ++i) {
        unsigned u = inw[lane * 16 + i];
        unsigned lo = u & 0xFFFFu;
        unsigned ec = (lo >> 7) & 0xFFu;
        if (lo == 0u || (ec >= 90u && ec <= 131u)) cnt++;
    }
    #pragma unroll
    for (int d = 32; d > 0; d >>= 1) cnt += __shfl_down(cnt, d, 64);
    return (cnt >= 512) ? 0 : 1;   // valid on lane 0: 0=bf16, 1=fp32
}

// ---------------------------------------------------------------------------
// k_count: 256 blocks, each histograms its own 256-token range. Writes (not
// adds) cnt[range][expert] -> no pre-zero kernel needed.
// ---------------------------------------------------------------------------
__global__ __launch_bounds__(256) void k_count(const int* __restrict__ gate,
                                               int* __restrict__ ws) {
    __shared__ int h[NUM_EXPERT];
    int t = threadIdx.x;
    if (t < NUM_EXPERT) h[t] = 0;
    __syncthreads();
    int g = gate[blockIdx.x * 256 + t] & 63;
    atomicAdd(&h[g], 1);
    __syncthreads();
    if (t < NUM_EXPERT) ws[WS_CNT + blockIdx.x * 64 + t] = h[t];
}

// ---------------------------------------------------------------------------
// k_plan_scatter:
//   blocks 0..255  : redundantly derive plan from counts matrix (cheap: 16K
//                    ints from L2), rank own 256 tokens via LDS cursors, write
//                    order; block 0 writes tile descriptors; then (big+fp32)
//                    wave-cooperative copy+convert of own rows into Asorted.
//   blocks 256..511: (big+fp32) weight fp32->bf16 conversion.
// ---------------------------------------------------------------------------
__global__ __launch_bounds__(256) void k_plan_scatter(
        const int* __restrict__ gate,
        const void* __restrict__ inp_,
        const void* __restrict__ weight_,
        int* __restrict__ ws,
        int big) {
    __shared__ int sFlag;
    int t = threadIdx.x;
    int lane = t & 63;
    int w = t >> 6;
    if (t < 64) {
        int f = detect_wave((const unsigned*)inp_, lane);
        if (t == 0) sFlag = f;
    }
    __syncthreads();
    int flag = sFlag;

    if (blockIdx.x >= NRANGE) {
        // ---- weight conversion role ----
        if (!big || flag != 1) return;
        const float* wf = (const float*)weight_;
        short* bw = (short*)((char*)ws + WS_BF16_OFF) + INP_ELEMS;
        const int NCHUNK = W_ELEMS / 8;            // 2,097,152 8-float chunks
        int idx = (int)(blockIdx.x - NRANGE) * 256 + t;
        for (int c = idx; c < NCHUNK; c += NRANGE * 256) {
            int f8 = c * 8;
            const float4* s = (const float4*)(wf + f8);
            float4 x = s[0], y = s[1];
            *(uint4*)(bw + f8) = (uint4){pk2(x.x, x.y), pk2(x.z, x.w),
                                         pk2(y.x, y.y), pk2(y.z, y.w)};
        }
        return;
    }

    // ---- plan (redundant per block, all derive identical values) ----
    __shared__ int pAll[4][NUM_EXPERT];
    __shared__ int pPre[4][NUM_EXPERT];
    __shared__ int sCur[NUM_EXPERT];
    __shared__ int sPos[256];
    int b = blockIdx.x;
    int e = t & 63;
    int q = t >> 6;                  // quarter of ranges
    const int* cnt = ws + WS_CNT;
    int sAll = 0, sPre = 0;
    for (int r = q * 64; r < q * 64 + 64; ++r) {
        int v = cnt[r * 64 + e];
        sAll += v;
        if (r < b) sPre += v;
    }
    pAll[q][e] = sAll;
    pPre[q][e] = sPre;
    __syncthreads();
    if (t < 64) {
        int T = pAll[0][lane] + pAll[1][lane] + pAll[2][lane] + pAll[3][lane];
        int P = pPre[0][lane] + pPre[1][lane] + pPre[2][lane] + pPre[3][lane];
        int ps = T;
        #pragma unroll
        for (int d = 1; d < 64; d <<= 1) { int v = __shfl_up(ps, d, 64); if (lane >= d) ps += v; }
        int off = ps - T;            // exclusive token prefix of expert `lane`
        sCur[lane] = off + P;        // this block's base for expert `lane`
        if (b == 0) {
            int nt = (T + BM - 1) >> 7;
            int pt = nt;
            #pragma unroll
            for (int d = 1; d < 64; d <<= 1) { int v = __shfl_up(pt, d, 64); if (lane >= d) pt += v; }
            int tb = pt - nt;
            for (int j = 0; j < nt; ++j) {
                int* tp = ws + WS_TILES + (tb + j) * 3;
                tp[0] = lane;
                tp[1] = off + j * BM;
                int rem = T - j * BM;
                tp[2] = rem < BM ? rem : BM;
            }
            if (lane == 63) ws[WS_NTILES] = pt;
        }
    }
    __syncthreads();

    // ---- rank own 256 tokens (LDS cursors; intra-block order arbitrary=fine) ----
    unsigned short* order = (unsigned short*)(ws + WS_ORDER);
    int tok = b * 256 + t;
    int ge = gate[tok] & 63;
    int pos = atomicAdd(&sCur[ge], 1);
    if ((unsigned)pos < (unsigned)N_TOKENS) order[pos] = (unsigned short)tok;
    sPos[t] = pos;
    __syncthreads();

    // ---- copy+convert own rows into Asorted (big + fp32 only) ----
    if (!big || flag != 1) return;
    short* Asrt = (short*)((char*)ws + WS_BF16_OFF);
    for (int i = w; i < 256; i += 4) {
        int pos_i = sPos[i];
        if ((unsigned)pos_i >= (unsigned)N_TOKENS) continue;
        const float4* src = (const float4*)((const float*)inp_ +
                            (size_t)(b * 256 + i) * IN_FEAT) + lane * 2;
        float4 x = src[0], y = src[1];
        *((uint4*)(Asrt + (size_t)pos_i * IN_FEAT) + lane) =
            (uint4){pk2(x.x, x.y), pk2(x.z, x.w), pk2(y.x, y.y), pk2(y.z, y.w)};
    }
}

#define COMPUTE(pA, pB)                                                        \
    {                                                                          \
        bf16x8 a_[4], b_[4];                                                   \
        _Pragma("unroll")                                                      \
        for (int t2 = 0; t2 < 4; ++t2) {                                       \
            a_[t2] = *(const bf16x8*)((pA) + t2 * 16 * BK);                    \
            b_[t2] = *(const bf16x8*)((pB) + t2 * 16 * BK);                    \
        }                                                                      \
        _Pragma("unroll")                                                      \
        for (int i_ = 0; i_ < 4; ++i_)                                         \
            _Pragma("unroll")                                                  \
            for (int j_ = 0; j_ < 4; ++j_)                                     \
                acc[i_][j_] = __builtin_amdgcn_mfma_f32_16x16x32_bf16(         \
                    a_[i_], b_[j_], acc[i_][j_], 0, 0, 0);                     \
    }

#define VMCNT0_BARRIER()                                                       \
    asm volatile("s_waitcnt vmcnt(0)" ::: "memory");                           \
    __builtin_amdgcn_s_barrier();

// ---------- BIG path GEMM: bf16, global_load_lds, 2-phase double buffer ----------
// Per K-step: stage(next)->other buffer, compute(cur), vmcnt(0)+barrier. The
// global-load latency hides under the MFMA+ds_read of the current step instead
// of being drained before it (§T3 minimum recipe). Source-side XOR chunk
// swizzle + same XOR on frag reads keeps ds_read_b128 at 2 lanes/bank (free).
__global__ __launch_bounds__(256) void k_moe_gemm_big(
        const void* __restrict__ inp_,
        const void* __restrict__ weight_,
        void* __restrict__ out_,
        const int* __restrict__ ws) {
    __shared__ __align__(16) short sA0[BM * BK], sA1[BM * BK];  // 8 KB each
    __shared__ __align__(16) short sB0[BN * BK], sB1[BN * BK];
    __shared__ int sTok[BM];
    __shared__ int sFlag;

    int tid = threadIdx.x;
    int lane = tid & 63;
    if (tid < 64) {
        int f = detect_wave((const unsigned*)inp_, lane);
        if (tid == 0) sFlag = f;
    }
    __syncthreads();
    int flag = sFlag;

    int ntiles = ws[WS_NTILES];
    if (ntiles > MAX_TILES) ntiles = MAX_TILES;
    if (ntiles < 0) ntiles = 0;
    int items = ntiles * NCOL;
    const unsigned short* order = (const unsigned short*)(ws + WS_ORDER);
    const short* Asrt = (const short*)((const char*)ws + WS_BF16_OFF);
    const short* Wb = flag ? Asrt + INP_ELEMS : (const short*)weight_;

    int w = tid >> 6;
    int wm = (w >> 1) * 64;
    int wn = (w & 1) * 64;
    int l15 = lane & 15;
    int quad = lane >> 4;

    // frag read addresses: linear row-major + XOR'd 16B chunk (row-dependent)
    int rowA = wm + l15;
    int rowB = wn + l15;
    int swA = rowA * BK + (quad ^ ((rowA >> 1) & 3)) * 8;
    int swB = rowB * BK + (quad ^ ((rowB >> 1) & 3)) * 8;
    const short* sAr0 = &sA0[swA];
    const short* sAr1 = &sA1[swA];
    const short* sBr0 = &sB0[swB];
    const short* sBr1 = &sB1[swB];

    // staging roles: wave w stages 1KB segments {2w,2w+1} of A and B
    int sr = lane >> 2;
    int cl = lane & 3;
    int rS0 = w * 32 + sr;
    int rS1 = rS0 + 16;
    int cg0 = (cl ^ ((rS0 >> 1) & 3)) * 16;   // byte offset of swizzled chunk
    int cg1 = (cl ^ ((rS1 >> 1) & 3)) * 16;
    short* dA0a = &sA0[w * 1024];
    short* dA1a = &sA0[w * 1024 + 512];
    short* dB0a = &sB0[w * 1024];
    short* dB1a = &sB0[w * 1024 + 512];
    short* dA0b = &sA1[w * 1024];
    short* dA1b = &sA1[w * 1024 + 512];
    short* dB0b = &sB1[w * 1024];
    short* dB1b = &sB1[w * 1024 + 512];

    for (int item = blockIdx.x; item < items; item += gridDim.x) {
        int tIdx = item >> 2;
        int n0 = (item & 3) * BN;
        const int* tile = ws + WS_TILES + tIdx * 3;
        int e = tile[0] & 63;
        int start = tile[1];
        int cnt = tile[2];
        cnt = cnt < 1 ? 1 : (cnt > BM ? BM : cnt);
        if (start < 0) start = 0;
        if (start > N_TOKENS - cnt) start = N_TOKENS - cnt;

        __syncthreads();   // prev item fully done (also drains epilogue stores)
        if (tid < BM) {
            int r = tid < cnt ? tid : (cnt - 1);
            sTok[tid] = (int)order[start + r];
        }
        __syncthreads();

        const char *gA0, *gA1;
        if (flag) {
            int srow0 = start + rS0; if (srow0 > N_TOKENS - 1) srow0 = N_TOKENS - 1;
            int srow1 = start + rS1; if (srow1 > N_TOKENS - 1) srow1 = N_TOKENS - 1;
            gA0 = (const char*)Asrt + (size_t)srow0 * (IN_FEAT * 2) + cg0;
            gA1 = (const char*)Asrt + (size_t)srow1 * (IN_FEAT * 2) + cg1;
        } else {
            gA0 = (const char*)inp_ + (size_t)sTok[rS0] * (IN_FEAT * 2) + cg0;
            gA1 = (const char*)inp_ + (size_t)sTok[rS1] * (IN_FEAT * 2) + cg1;
        }
        size_t wbase = (size_t)e * OUT_FEAT * IN_FEAT;
        const char* gB0 = (const char*)(Wb + wbase + (size_t)(n0 + rS0) * IN_FEAT) + cg0;
        const char* gB1 = (const char*)(Wb + wbase + (size_t)(n0 + rS1) * IN_FEAT) + cg1;

        f32x4 acc[4][4];
        #pragma unroll
        for (int i = 0; i < 4; ++i)
            #pragma unroll
            for (int j = 0; j < 4; ++j)
                acc[i][j] = (f32x4){0.f, 0.f, 0.f, 0.f};

        // prologue: stage step 0 -> buf a
        gll16(gA0, dA0a); gll16(gA1, dA1a); gll16(gB0, dB0a); gll16(gB1, dB1a);
        gA0 += 64; gA1 += 64; gB0 += 64; gB1 += 64;
        VMCNT0_BARRIER();

        #pragma unroll
        for (int it2 = 0; it2 < 8; ++it2) {
            // phase A: stage odd step -> buf b, compute buf a
            gll16(gA0, dA0b); gll16(gA1, dA1b); gll16(gB0, dB0b); gll16(gB1, dB1b);
            gA0 += 64; gA1 += 64; gB0 += 64; gB1 += 64;
            COMPUTE(sAr0, sBr0);
            VMCNT0_BARRIER();
            // phase B: stage even step -> buf a (except after last), compute buf b
            if (it2 < 7) {
                gll16(gA0, dA0a); gll16(gA1, dA1a); gll16(gB0, dB0a); gll16(gB1, dB1a);
                gA0 += 64; gA1 += 64; gB0 += 64; gB1 += 64;
            }
            COMPUTE(sAr1, sBr1);
            if (it2 < 7) {
                VMCNT0_BARRIER();
            }
        }

        // epilogue: D col = lane&15, row = quad*4 + reg [m89/m91]; NT stores
        #pragma unroll
        for (int i = 0; i < 4; ++i) {
            int mb = wm + i * 16 + quad * 4;
            #pragma unroll
            for (int r = 0; r < 4; ++r) {
                int m = mb + r;
                if (m < cnt) {
                    int tok = sTok[m];
                    if (flag) {
                        float* orow = (float*)out_ + (size_t)tok * OUT_FEAT + n0 + wn + l15;
                        #pragma unroll
                        for (int j = 0; j < 4; ++j)
                            __builtin_nontemporal_store(acc[i][j][r], orow + j * 16);
                    } else {
                        unsigned short* orow = (unsigned short*)out_ + (size_t)tok * OUT_FEAT + n0 + wn + l15;
                        #pragma unroll
                        for (int j = 0; j < 4; ++j)
                            __builtin_nontemporal_store(f2bu(acc[i][j][r]), orow + j * 16);
                    }
                }
            }
        }
    }
}

// ---------- MID path (meta-only ws): gathers from original inp/weight ----------
__global__ __launch_bounds__(256) void k_moe_gemm_mid(
        const void* __restrict__ inp_,
        const void* __restrict__ weight_,
        void* __restrict__ out_,
        const int* __restrict__ ws) {
    __shared__ __align__(16) short sA[BM * SK];
    __shared__ __align__(16) short sB[BN * SK];
    __shared__ int sTok[BM];
    __shared__ int sFlag;

    int tid = threadIdx.x;
    int lane = tid & 63;
    if (tid < 64) {
        int f = detect_wave((const unsigned*)inp_, lane);
        if (tid == 0) sFlag = f;
    }
    __syncthreads();
    int fp32 = sFlag;

    int ntiles = ws[WS_NTILES];
    if (ntiles > MAX_TILES) ntiles = MAX_TILES;
    int bx = blockIdx.y;
    if (bx >= ntiles) return;
    const int* tile = ws + WS_TILES + bx * 3;
    int e = tile[0] & 63;
    int start = tile[1];
    int cnt = tile[2];
    cnt = cnt < 1 ? 1 : (cnt > BM ? BM : cnt);
    if (start < 0) start = 0;
    if (start > N_TOKENS - cnt) start = N_TOKENS - cnt;
    int n0 = blockIdx.x * BN;
    const unsigned short* order = (const unsigned short*)(ws + WS_ORDER);

    if (tid < BM) {
        int r = tid < cnt ? tid : (cnt - 1);
        sTok[tid] = (int)order[start + r];
    }
    __syncthreads();

    int w = tid >> 6;
    int wm = (w >> 1) * 64;
    int wn = (w & 1) * 64;
    int l15 = lane & 15;
    int quad = lane >> 4;

    f32x4 acc[4][4];
    #pragma unroll
    for (int i = 0; i < 4; ++i)
        #pragma unroll
        for (int j = 0; j < 4; ++j)
            acc[i][j] = (f32x4){0.f, 0.f, 0.f, 0.f};

    const short* sAr = &sA[(wm + l15) * SK + quad * 8];
    const short* sBr = &sB[(wn + l15) * SK + quad * 8];

    if (fp32) {
        int ra = tid >> 1;
        int h = tid & 1;
        int tokA = sTok[ra];
        const float4* aG = (const float4*)((const float*)inp_ + (size_t)tokA * IN_FEAT) + h * 4;
        const float4* bG = (const float4*)((const float*)weight_ +
                           (size_t)(e * OUT_FEAT + n0 + ra) * IN_FEAT) + h * 4;
        uint4* sAd = (uint4*)&sA[ra * SK + h * 16];
        uint4* sBd = (uint4*)&sB[ra * SK + h * 16];

        for (int ks = 0; ks < K_STEPS; ++ks) {
            float4 a0 = aG[0], a1 = aG[1], a2 = aG[2], a3 = aG[3];
            float4 b0 = bG[0], b1 = bG[1], b2 = bG[2], b3 = bG[3];
            aG += 8; bG += 8;
            __syncthreads();
            sAd[0] = (uint4){pk2(a0.x, a0.y), pk2(a0.z, a0.w), pk2(a1.x, a1.y), pk2(a1.z, a1.w)};
            sAd[1] = (uint4){pk2(a2.x, a2.y), pk2(a2.z, a2.w), pk2(a3.x, a3.y), pk2(a3.z, a3.w)};
            sBd[0] = (uint4){pk2(b0.x, b0.y), pk2(b0.z, b0.w), pk2(b1.x, b1.y), pk2(b1.z, b1.w)};
            sBd[1] = (uint4){pk2(b2.x, b2.y), pk2(b2.z, b2.w), pk2(b3.x, b3.y), pk2(b3.z, b3.w)};
            __syncthreads();

            bf16x8 a[4], b[4];
            #pragma unroll
            for (int t = 0; t < 4; ++t) {
                a[t] = *(const bf16x8*)(sAr + t * 16 * SK);
                b[t] = *(const bf16x8*)(sBr + t * 16 * SK);
            }
            #pragma unroll
            for (int i = 0; i < 4; ++i)
                #pragma unroll
                for (int j = 0; j < 4; ++j)
                    acc[i][j] = __builtin_amdgcn_mfma_f32_16x16x32_bf16(a[i], b[j], acc[i][j], 0, 0, 0);
        }
    } else {
        int rr = tid >> 2;
        int qc = tid & 3;
        int tokA0 = sTok[rr];
        int tokA1 = sTok[rr + 64];
        const uint4* aG0 = (const uint4*)((const short*)inp_ + (size_t)tokA0 * IN_FEAT) + qc;
        const uint4* aG1 = (const uint4*)((const short*)inp_ + (size_t)tokA1 * IN_FEAT) + qc;
        const uint4* bG0 = (const uint4*)((const short*)weight_ +
                           (size_t)(e * OUT_FEAT + n0 + rr) * IN_FEAT) + qc;
        const uint4* bG1 = (const uint4*)((const short*)weight_ +
                           (size_t)(e * OUT_FEAT + n0 + rr + 64) * IN_FEAT) + qc;
        uint4* sAd0 = (uint4*)&sA[rr * SK + qc * 8];
        uint4* sAd1 = (uint4*)&sA[(rr + 64) * SK + qc * 8];
        uint4* sBd0 = (uint4*)&sB[rr * SK + qc * 8];
        uint4* sBd1 = (uint4*)&sB[(rr + 64) * SK + qc * 8];

        for (int ks = 0; ks < K_STEPS; ++ks) {
            uint4 va0 = *aG0, va1 = *aG1, vb0 = *bG0, vb1 = *bG1;
            aG0 += 4; aG1 += 4; bG0 += 4; bG1 += 4;
            __syncthreads();
            *sAd0 = va0; *sAd1 = va1; *sBd0 = vb0; *sBd1 = vb1;
            __syncthreads();

            bf16x8 a[4], b[4];
            #pragma unroll
            for (int t = 0; t < 4; ++t) {
                a[t] = *(const bf16x8*)(sAr + t * 16 * SK);
                b[t] = *(const bf16x8*)(sBr + t * 16 * SK);
            }
            #pragma unroll
            for (int i = 0; i < 4; ++i)
                #pragma unroll
                for (int j = 0; j < 4; ++j)
                    acc[i][j] = __builtin_amdgcn_mfma_f32_16x16x32_bf16(a[i], b[j], acc[i][j], 0, 0, 0);
        }
    }

    #pragma unroll
    for (int i = 0; i < 4; ++i) {
        int mb = wm + i * 16 + quad * 4;
        #pragma unroll
        for (int r = 0; r < 4; ++r) {
            int m = mb + r;
            if (m < cnt) {
                int tok = sTok[m];
                if (fp32) {
                    float* orow = (float*)out_ + (size_t)tok * OUT_FEAT + n0 + wn + l15;
                    #pragma unroll
                    for (int j = 0; j < 4; ++j)
                        __builtin_nontemporal_store(acc[i][j][r], orow + j * 16);
                } else {
                    unsigned short* orow = (unsigned short*)out_ + (size_t)tok * OUT_FEAT + n0 + wn + l15;
                    #pragma unroll
                    for (int j = 0; j < 4; ++j)
                        __builtin_nontemporal_store(f2bu(acc[i][j][r]), orow + j * 16);
                }
            }
        }
    }
}

// ws-light fallback: one block per token, VALU dot products
__global__ __launch_bounds__(256) void k_gemv(
        const void* __restrict__ inp_,
        const int* __restrict__ gate,
        const void* __restrict__ weight_,
        void* __restrict__ out_) {
    __shared__ float xf[IN_FEAT];
    __shared__ int sFlag;
    int t = threadIdx.x;
    if (t < 64) {
        int f = detect_wave((const unsigned*)inp_, t);
        if (t == 0) sFlag = f;
    }
    __syncthreads();
    int fp32 = sFlag;
    int tok = blockIdx.x;
    int e = gate[tok] & 63;
    if (fp32) {
        const float* xr = (const float*)inp_ + (size_t)tok * IN_FEAT;
        xf[2 * t] = xr[2 * t];
        xf[2 * t + 1] = xr[2 * t + 1];
        __syncthreads();
        #pragma unroll
        for (int rep = 0; rep < 2; ++rep) {
            int o = t + rep * 256;
            float s = 0.f;
            const float4* wr = (const float4*)((const float*)weight_ +
                               (size_t)(e * OUT_FEAT + o) * IN_FEAT);
            for (int k4 = 0; k4 < IN_FEAT / 4; ++k4) {
                float4 q = wr[k4];
                s += xf[4 * k4] * q.x + xf[4 * k4 + 1] * q.y
                   + xf[4 * k4 + 2] * q.z + xf[4 * k4 + 3] * q.w;
            }
            ((float*)out_)[(size_t)tok * OUT_FEAT + o] = s;
        }
    } else {
        const short* xr = (const short*)inp_ + (size_t)tok * IN_FEAT;
        xf[2 * t] = b2f(xr[2 * t]);
        xf[2 * t + 1] = b2f(xr[2 * t + 1]);
        __syncthreads();
        #pragma unroll
        for (int rep = 0; rep < 2; ++rep) {
            int o = t + rep * 256;
            float s = 0.f;
            const short4* wr = (const short4*)((const short*)weight_ +
                               (size_t)(e * OUT_FEAT + o) * IN_FEAT);
            for (int k4 = 0; k4 < IN_FEAT / 4; ++k4) {
                short4 q = wr[k4];
                s += xf[4 * k4] * b2f(q.x) + xf[4 * k4 + 1] * b2f(q.y)
                   + xf[4 * k4 + 2] * b2f(q.z) + xf[4 * k4 + 3] * b2f(q.w);
            }
            ((__hip_bfloat16*)out_)[(size_t)tok * OUT_FEAT + o] = __float2bfloat16(s);
        }
    }
}

extern "C" void kernel_launch(void* const* d_in, const int* in_sizes, int n_in,
                              void* d_out, int out_size, void* d_ws, size_t ws_size,
                              hipStream_t stream) {
    const void* inp    = d_in[0];
    const int*  gate   = (const int*)d_in[1];
    const void* weight = d_in[2];
    int* ws = (int*)d_ws;

    if (ws_size >= WS_BIG) {
        k_count<<<NRANGE, 256, 0, stream>>>(gate, ws);
        k_plan_scatter<<<2 * NRANGE, 256, 0, stream>>>(gate, inp, weight, ws, 1);
        k_moe_gemm_big<<<2048, 256, 0, stream>>>(inp, weight, d_out, ws);
    } else if (ws_size >= (size_t)WS_META_NEEDED) {
        k_count<<<NRANGE, 256, 0, stream>>>(gate, ws);
        k_plan_scatter<<<NRANGE, 256, 0, stream>>>(gate, inp, weight, ws, 0);
        dim3 grid(NCOL, MAX_TILES);
        k_moe_gemm_mid<<<grid, 256, 0, stream>>>(inp, weight, d_out, ws);
    } else {
        k_gemv<<<N_TOKENS, 256, 0, stream>>>(inp, gate, weight, d_out);
    }
}

// Round 7
// 325.000 us; speedup vs baseline: 1.5520x; 1.1065x over previous
//
#include <hip/hip_runtime.h>
#include <hip/hip_bf16.h>
#include <stdint.h>

#define N_TOKENS   65536
#define IN_FEAT    512
#define OUT_FEAT   512
#define NUM_EXPERT 64
#define BM 128
#define BN 128
#define BK 32
#define SK 36                    // padded LDS stride (mid-path kernel only)
#define K_STEPS (IN_FEAT / BK)   // 16
#define MAX_TILES 640            // true worst case: 512 + 64 = 576 tiles
#define NCOL (OUT_FEAT / BN)     // 4
#define NRANGE 256               // token ranges (256 tokens each)

// ws layout (int32 units):
//   [197] tile_count  [200..1928) tiles (e,start,cnt)x576
//   [2048..34816)  order ushort[65536] (128 KB)
//   [34816..51200) counts matrix cnt[range][expert] = 256x64 ints (64 KB)
// BIG extension (byte offsets):
//   [212992 ..)              bf16 copy of inp, TOKEN order (67,108,864 B)
//   [212992+2*INP_ELEMS ..)  bf16 copy of weight (33,554,432 B)
#define WS_NTILES 197
#define WS_TILES  200
#define WS_ORDER  2048
#define WS_CNT    34816
#define WS_META_NEEDED 204800    // bytes: through end of counts matrix

#define INP_ELEMS (N_TOKENS * IN_FEAT)               // 33,554,432
#define W_ELEMS   (NUM_EXPERT * OUT_FEAT * IN_FEAT)  // 16,777,216
#define WS_BF16_OFF 212992
#define WS_BIG ((size_t)WS_BF16_OFF + 2ull * INP_ELEMS + 2ull * W_ELEMS)  // ~100.9 MB

typedef __attribute__((ext_vector_type(8))) short bf16x8;
typedef __attribute__((ext_vector_type(4))) float f32x4;

__device__ __forceinline__ float b2f(short v) {
    union { float f; unsigned u; } z;
    z.u = ((unsigned)(unsigned short)v) << 16;
    return z.f;
}

__device__ __forceinline__ unsigned pk2(float a, float b) {
    union { __hip_bfloat16 h; unsigned short u; } x, y;
    x.h = __float2bfloat16(a);
    y.h = __float2bfloat16(b);
    return ((unsigned)y.u << 16) | (unsigned)x.u;
}

__device__ __forceinline__ unsigned short f2bu(float a) {
    union { __hip_bfloat16 h; unsigned short u; } x;
    x.h = __float2bfloat16(a);
    return x.u;
}

// async global->LDS, 16B per lane; LDS dest is wave-uniform base + lane*16
__device__ __forceinline__ void gll16(const void* g, short* l) {
    __builtin_amdgcn_global_load_lds(
        (const __attribute__((address_space(1))) unsigned*)g,
        (__attribute__((address_space(3))) unsigned*)l, 16, 0, 0);
}

// dtype detect by one wave: bf16-pair data has low-u16 exponent fields in the
// plausible band; fp32 low-u16 is random mantissa bits. Deterministic.
__device__ __forceinline__ int detect_wave(const unsigned* __restrict__ inw, int lane) {
    int cnt = 0;
    #pragma unroll
    for (int i = 0; i < 16; ++i) {
        unsigned u = inw[lane * 16 + i];
        unsigned lo = u & 0xFFFFu;
        unsigned ec = (lo >> 7) & 0xFFu;
        if (lo == 0u || (ec >= 90u && ec <= 131u)) cnt++;
    }
    #pragma unroll
    for (int d = 32; d > 0; d >>= 1) cnt += __shfl_down(cnt, d, 64);
    return (cnt >= 512) ? 0 : 1;   // valid on lane 0: 0=bf16, 1=fp32
}

// ---------------------------------------------------------------------------
// k_count: 256 blocks, each histograms its own 256-token range.
// ---------------------------------------------------------------------------
__global__ __launch_bounds__(256) void k_count(const int* __restrict__ gate,
                                               int* __restrict__ ws) {
    __shared__ int h[NUM_EXPERT];
    int t = threadIdx.x;
    if (t < NUM_EXPERT) h[t] = 0;
    __syncthreads();
    int g = gate[blockIdx.x * 256 + t] & 63;
    atomicAdd(&h[g], 1);
    __syncthreads();
    if (t < NUM_EXPERT) ws[WS_CNT + blockIdx.x * 64 + t] = h[t];
}

// ---------------------------------------------------------------------------
// k_prep:
//   blocks 0..255  : derive plan from counts matrix, rank own 256 tokens via
//                    LDS cursors, write order; block 0 writes tile descriptors.
//                    Then JOIN the streaming conversion below.
//   all blocks     : (big + fp32) grid-stride streaming fp32->bf16 conversion
//                    of inp (TOKEN order, no gather) + weight. NT loads on the
//                    read-once fp32 sources; normal stores keep bf16 LLC-hot.
// Output determinism: intra-block atomic ranking permutes WHICH slot a token
// gets within its block's sub-range, but out[tok] is position-independent, so
// final output is deterministic.
// ---------------------------------------------------------------------------
__global__ __launch_bounds__(256) void k_prep(
        const int* __restrict__ gate,
        const void* __restrict__ inp_,
        const void* __restrict__ weight_,
        int* __restrict__ ws,
        int big) {
    __shared__ int sFlag;
    int t = threadIdx.x;
    int lane = t & 63;
    if (t < 64) {
        int f = detect_wave((const unsigned*)inp_, lane);
        if (t == 0) sFlag = f;
    }
    __syncthreads();
    int flag = sFlag;

    if (blockIdx.x < NRANGE) {
        // ---- plan (redundant per block, all derive identical values) ----
        __shared__ int pAll[4][NUM_EXPERT];
        __shared__ int pPre[4][NUM_EXPERT];
        __shared__ int sCur[NUM_EXPERT];
        int b = blockIdx.x;
        int e = t & 63;
        int q = t >> 6;
        const int* cnt = ws + WS_CNT;
        int sAll = 0, sPre = 0;
        for (int r = q * 64; r < q * 64 + 64; ++r) {
            int v = cnt[r * 64 + e];
            sAll += v;
            if (r < b) sPre += v;
        }
        pAll[q][e] = sAll;
        pPre[q][e] = sPre;
        __syncthreads();
        if (t < 64) {
            int T = pAll[0][lane] + pAll[1][lane] + pAll[2][lane] + pAll[3][lane];
            int P = pPre[0][lane] + pPre[1][lane] + pPre[2][lane] + pPre[3][lane];
            int ps = T;
            #pragma unroll
            for (int d = 1; d < 64; d <<= 1) { int v = __shfl_up(ps, d, 64); if (lane >= d) ps += v; }
            int off = ps - T;            // exclusive token prefix of expert `lane`
            sCur[lane] = off + P;        // this block's base for expert `lane`
            if (b == 0) {
                int nt = (T + BM - 1) >> 7;
                int pt = nt;
                #pragma unroll
                for (int d = 1; d < 64; d <<= 1) { int v = __shfl_up(pt, d, 64); if (lane >= d) pt += v; }
                int tb = pt - nt;
                for (int j = 0; j < nt; ++j) {
                    int* tp = ws + WS_TILES + (tb + j) * 3;
                    tp[0] = lane;
                    tp[1] = off + j * BM;
                    int rem = T - j * BM;
                    tp[2] = rem < BM ? rem : BM;
                }
                if (lane == 63) ws[WS_NTILES] = pt;
            }
        }
        __syncthreads();

        // ---- rank own 256 tokens (LDS cursors; intra-block order arbitrary) ----
        unsigned short* order = (unsigned short*)(ws + WS_ORDER);
        int tok = b * 256 + t;
        int ge = gate[tok] & 63;
        int pos = atomicAdd(&sCur[ge], 1);
        if ((unsigned)pos < (unsigned)N_TOKENS) order[pos] = (unsigned short)tok;
        // fall through: join streaming conversion
    }

    // ---- streaming conversion (big + fp32 only), all blocks ----
    if (!big || flag != 1) return;
    const float* inpf = (const float*)inp_;
    const float* wf   = (const float*)weight_;
    short* bi = (short*)((char*)ws + WS_BF16_OFF);
    short* bw = bi + INP_ELEMS;
    const long long NC = (long long)(INP_ELEMS + W_ELEMS) / 8;  // 8-float chunks
    long long idx = (long long)blockIdx.x * 256 + t;
    long long stride = (long long)gridDim.x * 256;
    for (long long c = idx; c < NC; c += stride) {
        long long f8 = c * 8;
        const f32x4* s;
        uint4* d;
        if (f8 < INP_ELEMS) {
            s = (const f32x4*)(inpf + f8);
            d = (uint4*)(bi + f8);
        } else {
            long long g = f8 - INP_ELEMS;
            s = (const f32x4*)(wf + g);
            d = (uint4*)(bw + g);
        }
        f32x4 x = __builtin_nontemporal_load(s);
        f32x4 y = __builtin_nontemporal_load(s + 1);
        *d = (uint4){pk2(x[0], x[1]), pk2(x[2], x[3]),
                     pk2(y[0], y[1]), pk2(y[2], y[3])};
    }
}

#define COMPUTE(pA, pB)                                                        \
    {                                                                          \
        bf16x8 a_[4], b_[4];                                                   \
        _Pragma("unroll")                                                      \
        for (int t2 = 0; t2 < 4; ++t2) {                                       \
            a_[t2] = *(const bf16x8*)((pA) + t2 * 16 * BK);                    \
            b_[t2] = *(const bf16x8*)((pB) + t2 * 16 * BK);                    \
        }                                                                      \
        _Pragma("unroll")                                                      \
        for (int i_ = 0; i_ < 4; ++i_)                                         \
            _Pragma("unroll")                                                  \
            for (int j_ = 0; j_ < 4; ++j_)                                     \
                acc[i_][j_] = __builtin_amdgcn_mfma_f32_16x16x32_bf16(         \
                    a_[i_], b_[j_], acc[i_][j_], 0, 0, 0);                     \
    }

#define STAGE(kk, pa, pb)                                                      \
    gll16(gA0 + (size_t)(kk) * 64, (pa));                                      \
    gll16(gA1 + (size_t)(kk) * 64, (pa) + 512);                                \
    gll16(gB0 + (size_t)(kk) * 64, (pb));                                      \
    gll16(gB1 + (size_t)(kk) * 64, (pb) + 512);

// Fenced drain + barrier: vmcnt(0) (all this wave's LDS-DMA landed) then
// s_barrier (all waves reached the same point). Both carry "memory" clobbers
// so the compiler cannot move LDS reads/writes or gll16 across them (rule #18
// class). This is R4's proven-correct structure; the counted-vmcnt(4) variant
// raced on HW (R5 nondeterministic, R6 corrupt) and is abandoned.
#define DRAIN_BARRIER()                                                        \
    asm volatile("s_waitcnt vmcnt(0)" ::: "memory");                           \
    asm volatile("s_barrier" ::: "memory")

// ---------- BIG path GEMM: bf16, gather-A, double buffer ----------
// Per K-step: issue STAGE(k+1) into the other buffer, COMPUTE(k) (the stage
// loads drain UNDER the MFMAs), then vmcnt(0)+barrier. One barrier per step;
// load latency is hidden by compute, not exposed before it.
// Source-side XOR chunk swizzle + same XOR on frag reads -> ~2 lanes/bank.
// Items are XCD-chunked: each XCD's 256 blocks own a contiguous item range so
// the 4 column-items sharing an A-tile hit the same XCD L2.
__global__ __launch_bounds__(256) void k_moe_gemm_big(
        const void* __restrict__ inp_,
        const void* __restrict__ weight_,
        void* __restrict__ out_,
        const int* __restrict__ ws) {
    __shared__ __align__(16) short sA0[BM * BK], sA1[BM * BK];  // 8 KB each
    __shared__ __align__(16) short sB0[BN * BK], sB1[BN * BK];
    __shared__ int sTok[BM];
    __shared__ int sFlag;

    int tid = threadIdx.x;
    int lane = tid & 63;
    if (tid < 64) {
        int f = detect_wave((const unsigned*)inp_, lane);
        if (tid == 0) sFlag = f;
    }
    __syncthreads();
    int flag = sFlag;

    int ntiles = ws[WS_NTILES];
    if (ntiles > MAX_TILES) ntiles = MAX_TILES;
    if (ntiles < 0) ntiles = 0;
    int items = ntiles * NCOL;
    const unsigned short* order = (const unsigned short*)(ws + WS_ORDER);
    const char* Abase = flag ? (const char*)ws + WS_BF16_OFF : (const char*)inp_;
    const char* Wbase = flag ? (const char*)ws + WS_BF16_OFF + 2ull * INP_ELEMS
                             : (const char*)weight_;

    int w = tid >> 6;
    int wm = (w >> 1) * 64;
    int wn = (w & 1) * 64;
    int l15 = lane & 15;
    int quad = lane >> 4;

    // frag read addresses: linear row-major + XOR'd 16B chunk (row-dependent)
    int rowA = wm + l15;
    int rowB = wn + l15;
    int swA = rowA * BK + (quad ^ ((rowA >> 1) & 3)) * 8;
    int swB = rowB * BK + (quad ^ ((rowB >> 1) & 3)) * 8;
    const short* sAr0 = &sA0[swA];
    const short* sAr1 = &sA1[swA];
    const short* sBr0 = &sB0[swB];
    const short* sBr1 = &sB1[swB];

    // staging roles: wave w stages 1KB segments {2w,2w+1} of A and B
    int sr = lane >> 2;
    int cl = lane & 3;
    int rS0 = w * 32 + sr;
    int rS1 = rS0 + 16;
    int cg0 = (cl ^ ((rS0 >> 1) & 3)) * 16;   // byte offset of swizzled chunk
    int cg1 = (cl ^ ((rS1 >> 1) & 3)) * 16;
    short* dA0 = &sA0[w * 1024];
    short* dB0 = &sB0[w * 1024];
    short* dA1 = &sA1[w * 1024];
    short* dB1 = &sB1[w * 1024];

    // XCD-chunked item partition (gridDim.x = 2048 -> 256 blocks per XCD)
    int xcd = blockIdx.x & 7;
    int sub = blockIdx.x >> 3;
    int chunk = (items + 7) >> 3;

    for (int i = sub; i < chunk; i += 256) {
        int item = xcd * chunk + i;
        if (item >= items) break;
        int tIdx = item >> 2;
        int n0 = (item & 3) * BN;
        const int* tile = ws + WS_TILES + tIdx * 3;
        int e = tile[0] & 63;
        int start = tile[1];
        int cnt = tile[2];
        cnt = cnt < 1 ? 1 : (cnt > BM ? BM : cnt);
        if (start < 0) start = 0;
        if (start > N_TOKENS - cnt) start = N_TOKENS - cnt;

        __syncthreads();   // prev item fully done (full drain; protects sTok/LDS)
        if (tid < BM) {
            int r = tid < cnt ? tid : (cnt - 1);
            sTok[tid] = (int)order[start + r];
        }
        __syncthreads();

        const char* gA0 = Abase + (size_t)sTok[rS0] * (IN_FEAT * 2) + cg0;
        const char* gA1 = Abase + (size_t)sTok[rS1] * (IN_FEAT * 2) + cg1;
        size_t wbase = (size_t)e * OUT_FEAT * IN_FEAT * 2;
        const char* gB0 = Wbase + wbase + (size_t)(n0 + rS0) * (IN_FEAT * 2) + cg0;
        const char* gB1 = Wbase + wbase + (size_t)(n0 + rS1) * (IN_FEAT * 2) + cg1;

        f32x4 acc[4][4];
        #pragma unroll
        for (int ii = 0; ii < 4; ++ii)
            #pragma unroll
            for (int jj = 0; jj < 4; ++jj)
                acc[ii][jj] = (f32x4){0.f, 0.f, 0.f, 0.f};

        // prologue: stage step 0 -> buf 0, drain, barrier
        STAGE(0, dA0, dB0);
        DRAIN_BARRIER();

        #pragma unroll
        for (int k = 0; k < K_STEPS; ++k) {
            // issue next stage into the OTHER buffer (its last readers finished
            // at the barrier ending step k-1)
            if (k + 1 < K_STEPS) {
                if ((k + 1) & 1) { STAGE(k + 1, dA1, dB1); }
                else             { STAGE(k + 1, dA0, dB0); }
            }
            // compute current buffer; next-stage loads drain under the MFMAs
            if (k & 1) { COMPUTE(sAr1, sBr1); }
            else       { COMPUTE(sAr0, sBr0); }
            if (k + 1 < K_STEPS) {
                DRAIN_BARRIER();   // my stage(k+1) landed + all waves done reading buf k
            }
        }

        // epilogue: D col = lane&15, row = quad*4 + reg [m89/m91]; NT stores
        #pragma unroll
        for (int ii = 0; ii < 4; ++ii) {
            int mb = wm + ii * 16 + quad * 4;
            #pragma unroll
            for (int r = 0; r < 4; ++r) {
                int m = mb + r;
                if (m < cnt) {
                    int tok = sTok[m];
                    if (flag) {
                        float* orow = (float*)out_ + (size_t)tok * OUT_FEAT + n0 + wn + l15;
                        #pragma unroll
                        for (int j = 0; j < 4; ++j)
                            __builtin_nontemporal_store(acc[ii][j][r], orow + j * 16);
                    } else {
                        unsigned short* orow = (unsigned short*)out_ + (size_t)tok * OUT_FEAT + n0 + wn + l15;
                        #pragma unroll
                        for (int j = 0; j < 4; ++j)
                            __builtin_nontemporal_store(f2bu(acc[ii][j][r]), orow + j * 16);
                    }
                }
            }
        }
    }
}

// ---------- MID path (meta-only ws): gathers from original inp/weight ----------
__global__ __launch_bounds__(256) void k_moe_gemm_mid(
        const void* __restrict__ inp_,
        const void* __restrict__ weight_,
        void* __restrict__ out_,
        const int* __restrict__ ws) {
    __shared__ __align__(16) short sA[BM * SK];
    __shared__ __align__(16) short sB[BN * SK];
    __shared__ int sTok[BM];
    __shared__ int sFlag;

    int tid = threadIdx.x;
    int lane = tid & 63;
    if (tid < 64) {
        int f = detect_wave((const unsigned*)inp_, lane);
        if (tid == 0) sFlag = f;
    }
    __syncthreads();
    int fp32 = sFlag;

    int ntiles = ws[WS_NTILES];
    if (ntiles > MAX_TILES) ntiles = MAX_TILES;
    int bx = blockIdx.y;
    if (bx >= ntiles) return;
    const int* tile = ws + WS_TILES + bx * 3;
    int e = tile[0] & 63;
    int start = tile[1];
    int cnt = tile[2];
    cnt = cnt < 1 ? 1 : (cnt > BM ? BM : cnt);
    if (start < 0) start = 0;
    if (start > N_TOKENS - cnt) start = N_TOKENS - cnt;
    int n0 = blockIdx.x * BN;
    const unsigned short* order = (const unsigned short*)(ws + WS_ORDER);

    if (tid < BM) {
        int r = tid < cnt ? tid : (cnt - 1);
        sTok[tid] = (int)order[start + r];
    }
    __syncthreads();

    int w = tid >> 6;
    int wm = (w >> 1) * 64;
    int wn = (w & 1) * 64;
    int l15 = lane & 15;
    int quad = lane >> 4;

    f32x4 acc[4][4];
    #pragma unroll
    for (int i = 0; i < 4; ++i)
        #pragma unroll
        for (int j = 0; j < 4; ++j)
            acc[i][j] = (f32x4){0.f, 0.f, 0.f, 0.f};

    const short* sAr = &sA[(wm + l15) * SK + quad * 8];
    const short* sBr = &sB[(wn + l15) * SK + quad * 8];

    if (fp32) {
        int ra = tid >> 1;
        int h = tid & 1;
        int tokA = sTok[ra];
        const float4* aG = (const float4*)((const float*)inp_ + (size_t)tokA * IN_FEAT) + h * 4;
        const float4* bG = (const float4*)((const float*)weight_ +
                           (size_t)(e * OUT_FEAT + n0 + ra) * IN_FEAT) + h * 4;
        uint4* sAd = (uint4*)&sA[ra * SK + h * 16];
        uint4* sBd = (uint4*)&sB[ra * SK + h * 16];

        for (int ks = 0; ks < K_STEPS; ++ks) {
            float4 a0 = aG[0], a1 = aG[1], a2 = aG[2], a3 = aG[3];
            float4 b0 = bG[0], b1 = bG[1], b2 = bG[2], b3 = bG[3];
            aG += 8; bG += 8;
            __syncthreads();
            sAd[0] = (uint4){pk2(a0.x, a0.y), pk2(a0.z, a0.w), pk2(a1.x, a1.y), pk2(a1.z, a1.w)};
            sAd[1] = (uint4){pk2(a2.x, a2.y), pk2(a2.z, a2.w), pk2(a3.x, a3.y), pk2(a3.z, a3.w)};
            sBd[0] = (uint4){pk2(b0.x, b0.y), pk2(b0.z, b0.w), pk2(b1.x, b1.y), pk2(b1.z, b1.w)};
            sBd[1] = (uint4){pk2(b2.x, b2.y), pk2(b2.z, b2.w), pk2(b3.x, b3.y), pk2(b3.z, b3.w)};
            __syncthreads();

            bf16x8 a[4], b[4];
            #pragma unroll
            for (int t = 0; t < 4; ++t) {
                a[t] = *(const bf16x8*)(sAr + t * 16 * SK);
                b[t] = *(const bf16x8*)(sBr + t * 16 * SK);
            }
            #pragma unroll
            for (int i = 0; i < 4; ++i)
                #pragma unroll
                for (int j = 0; j < 4; ++j)
                    acc[i][j] = __builtin_amdgcn_mfma_f32_16x16x32_bf16(a[i], b[j], acc[i][j], 0, 0, 0);
        }
    } else {
        int rr = tid >> 2;
        int qc = tid & 3;
        int tokA0 = sTok[rr];
        int tokA1 = sTok[rr + 64];
        const uint4* aG0 = (const uint4*)((const short*)inp_ + (size_t)tokA0 * IN_FEAT) + qc;
        const uint4* aG1 = (const uint4*)((const short*)inp_ + (size_t)tokA1 * IN_FEAT) + qc;
        const uint4* bG0 = (const uint4*)((const short*)weight_ +
                           (size_t)(e * OUT_FEAT + n0 + rr) * IN_FEAT) + qc;
        const uint4* bG1 = (const uint4*)((const short*)weight_ +
                           (size_t)(e * OUT_FEAT + n0 + rr + 64) * IN_FEAT) + qc;
        uint4* sAd0 = (uint4*)&sA[rr * SK + qc * 8];
        uint4* sAd1 = (uint4*)&sA[(rr + 64) * SK + qc * 8];
        uint4* sBd0 = (uint4*)&sB[rr * SK + qc * 8];
        uint4* sBd1 = (uint4*)&sB[(rr + 64) * SK + qc * 8];

        for (int ks = 0; ks < K_STEPS; ++ks) {
            uint4 va0 = *aG0, va1 = *aG1, vb0 = *bG0, vb1 = *bG1;
            aG0 += 4; aG1 += 4; bG0 += 4; bG1 += 4;
            __syncthreads();
            *sAd0 = va0; *sAd1 = va1; *sBd0 = vb0; *sBd1 = vb1;
            __syncthreads();

            bf16x8 a[4], b[4];
            #pragma unroll
            for (int t = 0; t < 4; ++t) {
                a[t] = *(const bf16x8*)(sAr + t * 16 * SK);
                b[t] = *(const bf16x8*)(sBr + t * 16 * SK);
            }
            #pragma unroll
            for (int i = 0; i < 4; ++i)
                #pragma unroll
                for (int j = 0; j < 4; ++j)
                    acc[i][j] = __builtin_amdgcn_mfma_f32_16x16x32_bf16(a[i], b[j], acc[i][j], 0, 0, 0);
        }
    }

    #pragma unroll
    for (int i = 0; i < 4; ++i) {
        int mb = wm + i * 16 + quad * 4;
        #pragma unroll
        for (int r = 0; r < 4; ++r) {
            int m = mb + r;
            if (m < cnt) {
                int tok = sTok[m];
                if (fp32) {
                    float* orow = (float*)out_ + (size_t)tok * OUT_FEAT + n0 + wn + l15;
                    #pragma unroll
                    for (int j = 0; j < 4; ++j)
                        __builtin_nontemporal_store(acc[i][j][r], orow + j * 16);
                } else {
                    unsigned short* orow = (unsigned short*)out_ + (size_t)tok * OUT_FEAT + n0 + wn + l15;
                    #pragma unroll
                    for (int j = 0; j < 4; ++j)
                        __builtin_nontemporal_store(f2bu(acc[i][j][r]), orow + j * 16);
                }
            }
        }
    }
}

// ws-light fallback: one block per token, VALU dot products
__global__ __launch_bounds__(256) void k_gemv(
        const void* __restrict__ inp_,
        const int* __restrict__ gate,
        const void* __restrict__ weight_,
        void* __restrict__ out_) {
    __shared__ float xf[IN_FEAT];
    __shared__ int sFlag;
    int t = threadIdx.x;
    if (t < 64) {
        int f = detect_wave((const unsigned*)inp_, t);
        if (t == 0) sFlag = f;
    }
    __syncthreads();
    int fp32 = sFlag;
    int tok = blockIdx.x;
    int e = gate[tok] & 63;
    if (fp32) {
        const float* xr = (const float*)inp_ + (size_t)tok * IN_FEAT;
        xf[2 * t] = xr[2 * t];
        xf[2 * t + 1] = xr[2 * t + 1];
        __syncthreads();
        #pragma unroll
        for (int rep = 0; rep < 2; ++rep) {
            int o = t + rep * 256;
            float s = 0.f;
            const float4* wr = (const float4*)((const float*)weight_ +
                               (size_t)(e * OUT_FEAT + o) * IN_FEAT);
            for (int k4 = 0; k4 < IN_FEAT / 4; ++k4) {
                float4 q = wr[k4];
                s += xf[4 * k4] * q.x + xf[4 * k4 + 1] * q.y
                   + xf[4 * k4 + 2] * q.z + xf[4 * k4 + 3] * q.w;
            }
            ((float*)out_)[(size_t)tok * OUT_FEAT + o] = s;
        }
    } else {
        const short* xr = (const short*)inp_ + (size_t)tok * IN_FEAT;
        xf[2 * t] = b2f(xr[2 * t]);
        xf[2 * t + 1] = b2f(xr[2 * t + 1]);
        __syncthreads();
        #pragma unroll
        for (int rep = 0; rep < 2; ++rep) {
            int o = t + rep * 256;
            float s = 0.f;
            const short4* wr = (const short4*)((const short*)weight_ +
                               (size_t)(e * OUT_FEAT + o) * IN_FEAT);
            for (int k4 = 0; k4 < IN_FEAT / 4; ++k4) {
                short4 q = wr[k4];
                s += xf[4 * k4] * b2f(q.x) + xf[4 * k4 + 1] * b2f(q.y)
                   + xf[4 * k4 + 2] * b2f(q.z) + xf[4 * k4 + 3] * b2f(q.w);
            }
            ((__hip_bfloat16*)out_)[(size_t)tok * OUT_FEAT + o] = __float2bfloat16(s);
        }
    }
}

extern "C" void kernel_launch(void* const* d_in, const int* in_sizes, int n_in,
                              void* d_out, int out_size, void* d_ws, size_t ws_size,
                              hipStream_t stream) {
    const void* inp    = d_in[0];
    const int*  gate   = (const int*)d_in[1];
    const void* weight = d_in[2];
    int* ws = (int*)d_ws;

    if (ws_size >= WS_BIG) {
        k_count<<<NRANGE, 256, 0, stream>>>(gate, ws);
        k_prep<<<2048, 256, 0, stream>>>(gate, inp, weight, ws, 1);
        k_moe_gemm_big<<<2048, 256, 0, stream>>>(inp, weight, d_out, ws);
    } else if (ws_size >= (size_t)WS_META_NEEDED) {
        k_count<<<NRANGE, 256, 0, stream>>>(gate, ws);
        k_prep<<<NRANGE, 256, 0, stream>>>(gate, inp, weight, ws, 0);
        dim3 grid(NCOL, MAX_TILES);
        k_moe_gemm_mid<<<grid, 256, 0, stream>>>(inp, weight, d_out, ws);
    } else {
        k_gemv<<<N_TOKENS, 256, 0, stream>>>(inp, gate, weight, d_out);
    }
}